// Round 5
// baseline (74.374 us; speedup 1.0000x reference)
//
#include <hip/hip_runtime.h>
#include <stdint.h>

// DTM layer: B=4, C=3, H=W=64. Unit-spaced lattice => dist^2 = di^2 + dj^2.
// Distance-sorted offset table is a compile-time constant (constexpr counting
// sort). Per pixel: walk offsets in increasing d2, accumulate weight until
// crossing bound = 0.05*sum(w), interpolate within the crossing element.
// Equal-d2 shells are order-invariant; the reference's max_k clip never binds.
//
// Round-5 structure: one 1024-thread block (16 waves) per (b,c,row).
//  - Weights live in a ZERO-PADDED LDS array wp[64][192] (column halo), so
//    column-validity checks vanish and row-validity is a wave-uniform SCALAR
//    skip (saves ~50% of phase-A ds_reads + VALU).
//  - Phase A: wave v computes chunk-v (64 sorted entries) partial sums
//    (mass, d2*mass) for all 64 pixels; entries preloaded to VGPRs (one
//    coalesced load/wave) and broadcast via v_readlane -> no s_loads in the
//    lgkm queue, gathers batch cleanly.
//  - Phase B (wave 0): scan 16 chunk summaries per pixel, walk the 64 entries
//    of the per-lane crossing chunk (entries from a transposed LDS copy
//    eb[k*16+c]: distinct cstar -> distinct banks, conflict-free), plus a
//    practically-never-taken exact fallback past the 1024-entry window.
//  - __launch_bounds__(1024, 8): VGPR<=64 -> 2 blocks/CU (32 waves/CU).

#define HW     4096
#define NOFF   16129   // 127*127
#define NPAD   16384
#define NBIN   8192    // max d2 = 63^2+63^2 = 7938
#define NCHUNK 16
#define WPS    192     // padded row stride (words); data at columns [64,127]
#define WPN    (64 * WPS)

struct Ent { uint32_t off; float d2; };   // off = (di+63)<<7 | (dj+63)
struct Tables { Ent e[NPAD]; };

constexpr Tables make_tables() {
    Tables t{};
    int cnt[NBIN] = {};
    for (int idx = 0; idx < NOFF; ++idx) {
        int di = idx / 127 - 63, dj = idx % 127 - 63;
        cnt[di * di + dj * dj]++;
    }
    int run = 0;
    for (int b = 0; b < NBIN; ++b) { int c = cnt[b]; cnt[b] = run; run += c; }
    for (int idx = 0; idx < NOFF; ++idx) {
        int di = idx / 127 - 63, dj = idx % 127 - 63;
        int d2 = di * di + dj * dj;
        int pos = cnt[d2]++;
        t.e[pos].off = (uint32_t)((di + 63) << 7) | (uint32_t)(dj + 63);
        t.e[pos].d2  = (float)d2;
    }
    for (int p = NOFF; p < NPAD; ++p) {
        t.e[p].off = 127u;   // di = -63 (row always invalid for fallback), dj = 64
        t.e[p].d2  = 0.0f;
    }
    return t;
}

__device__ const Tables g_t = make_tables();

__global__ __launch_bounds__(1024, 8) void dtm_kernel(const float* __restrict__ x,
                                                      float* __restrict__ out) {
    __shared__ float  wp[WPN];            // 48 KB zero-padded weights
    __shared__ float2 summ[NCHUNK][64];   // 8 KB chunk partials
    __shared__ uint2  eb[1024];           // 8 KB entries, eb[k*16+c] = chunk c entry k
    __shared__ float  red[16];

    int bc   = blockIdx.x >> 6;
    int pi   = blockIdx.x & 63;   // row (uniform)
    int tid  = threadIdx.x;
    int lane = tid & 63;          // pixel column
    int wv   = tid >> 6;          // wave id = chunk id

    // zero-fill padded weight array (3 float4 per thread)
    float4 z = make_float4(0.f, 0.f, 0.f, 0.f);
    float4* wp4 = (float4*)wp;
    wp4[tid] = z; wp4[tid + 1024] = z; wp4[tid + 2048] = z;

    // global loads (issue before the barrier, use after)
    const float4* xb = (const float4*)(x + (size_t)bc * HW);
    float4 v = xb[tid];
    const uint2* gt = (const uint2*)g_t.e;
    uint2 ev  = gt[tid];                              // phase-A: chunk wv, entry lane
    uint2 ebv = gt[((tid & 15) << 6) | (tid >> 4)];   // transposed for eb

    __syncthreads();

    // stage x into padded wp (16B-aligned: (row*192 + 64 + col)*4, col mult of 4)
    {
        int row = tid >> 4;
        int col = (tid & 15) << 2;
        *(float4*)&wp[row * WPS + 64 + col] = v;
    }
    eb[tid] = ebv;
    float s = (v.x + v.y) + (v.z + v.w);
    #pragma unroll
    for (int off = 32; off >= 1; off >>= 1) s += __shfl_down(s, off, 64);
    if (lane == 0) red[wv] = s;
    __syncthreads();

    // ---- phase A: chunk-wv partial sums for all 64 pixels of row pi ----
    float mass = 0.f, d2m = 0.f;
    #pragma unroll 16
    for (int k = 0; k < 64; ++k) {
        uint32_t eo = (uint32_t)__builtin_amdgcn_readlane((int)ev.x, k);
        int qi = pi + (int)((eo >> 7) & 127u) - 63;      // uniform (SALU)
        if ((unsigned)qi < 64u) {                        // scalar skip: ~50% of entries
            float d2 = __uint_as_float(
                (uint32_t)__builtin_amdgcn_readlane(__float_as_int(0.f) | (int)ev.y, k));
            float wq = wp[qi * WPS + 64 + ((int)(eo & 127u) - 63) + lane];
            mass += wq;
            d2m = fmaf(d2, wq, d2m);
        }
    }
    summ[wv][lane] = make_float2(mass, d2m);
    __syncthreads();
    if (wv != 0) return;

    // ---- phase B (wave 0): per-lane pixel = column lane of row pi ----
    float bound = 0.f;
    #pragma unroll
    for (int i = 0; i < 16; ++i) bound += red[i];
    bound *= 0.05f;

    // scan chunks 0..14 (chunk 15 crossing handled naturally by the walk)
    float rem = bound, cumd = 0.f;
    int cstar = 15;
    bool found = false;
    #pragma unroll
    for (int c = 0; c < 15; ++c) {
        float2 p = summ[c][lane];
        bool cross = (!found) && (p.x >= rem);
        cstar = cross ? c : cstar;
        bool adv = (!found) && (!cross);
        rem  = adv ? rem - p.x : rem;
        cumd = adv ? cumd + p.y : cumd;
        found = found || cross;
    }

    // walk the 64 entries of the crossing chunk
    float val = 0.f;
    bool done = false;
    #pragma unroll 8
    for (int k = 0; k < 64; ++k) {
        uint2 e = eb[(k << 4) | cstar];
        int qi = pi + (int)((e.x >> 7) & 127u) - 63;
        int jj = 64 + (int)(e.x & 127u) - 63 + lane;
        float wq = wp[((qi & 63) * WPS) + jj];
        bool ok = ((unsigned)qi < 64u) && !done;
        wq = ok ? wq : 0.f;
        float d2 = __uint_as_float(e.y);
        bool cross = (!done) && (wq >= rem);
        val  = cross ? fmaf(d2, rem, cumd) : val;
        done = done || cross;
        cumd = fmaf(d2, wq, cumd);
        rem -= wq;
    }
    int pos = (cstar << 6) + 64;

    // exact fallback (ulp-boundary chunk detection or crossing past the
    // speculative window); practically never iterates
    while (__any(!done)) {
        int idx = pos < NPAD ? pos : NPAD - 1;
        uint2 e = gt[idx];
        int qi = pi + (int)((e.x >> 7) & 127u) - 63;
        int jj = 64 + (int)(e.x & 127u) - 63 + lane;
        float wq = wp[((qi & 63) * WPS) + jj];
        bool ok = ((unsigned)qi < 64u) && !done;
        wq = ok ? wq : 0.f;
        float d2 = __uint_as_float(e.y);
        bool cross = (!done) && ((wq >= rem) || (pos >= NPAD));
        val  = cross ? fmaf(d2, rem, cumd) : val;
        done = done || cross;
        cumd = fmaf(d2, wq, cumd);
        rem -= wq;
        pos++;
    }

    out[(size_t)bc * HW + (pi << 6) + lane] = sqrtf(val / bound);
}

extern "C" void kernel_launch(void* const* d_in, const int* in_sizes, int n_in,
                              void* d_out, int out_size, void* d_ws, size_t ws_size,
                              hipStream_t stream) {
    const float* x = (const float*)d_in[0];
    float* out = (float*)d_out;
    int BC = in_sizes[0] / HW;   // 12 for (4,3,64,64)
    dtm_kernel<<<BC * 64, 1024, 0, stream>>>(x, out);
}